// Round 6
// baseline (204.146 us; speedup 1.0000x reference)
//
#include <hip/hip_runtime.h>
#include <hip/hip_bf16.h>
#include <math.h>

#define NN 1024

typedef short bf16x8 __attribute__((ext_vector_type(8)));
typedef float f32x4 __attribute__((ext_vector_type(4)));

__device__ __forceinline__ unsigned rne_u(float x) {
    unsigned u = __float_as_uint(x);
    return u + 0x7fffu + ((u >> 16) & 1u);
}
__device__ __forceinline__ float bf16_up_bits(unsigned hi16) {
    return __uint_as_float(hi16 << 16);
}
__device__ __forceinline__ unsigned pair_pack(float a, float b) {   // a->low, b->high, RNE
    return (rne_u(a) >> 16) | (rne_u(b) & 0xffff0000u);
}
// packed fp32x2 -> bf16x2 (v_cvt_pk_bf16_f32 on gfx950)
__device__ __forceinline__ unsigned pack2(float a, float b) {
    __hip_bfloat162 h = __float22bfloat162_rn(make_float2(a, b));
    unsigned u;
    __builtin_memcpy(&u, &h, 4);
    return u;
}

union U16 { uint4 u; bf16x8 v; };
union P4 { unsigned w[4]; bf16x8 v; };

// h1 fragment: relu(x + c) -> bf16 RNE, element e at k = q*8+e
__device__ __forceinline__ bf16x8 mk_frag(float4 x0, float4 x1, float4 c0, float4 c1) {
    P4 u;
    u.w[0] = pack2(fmaxf(x0.x + c0.x, 0.f), fmaxf(x0.y + c0.y, 0.f));
    u.w[1] = pack2(fmaxf(x0.z + c0.z, 0.f), fmaxf(x0.w + c0.w, 0.f));
    u.w[2] = pack2(fmaxf(x1.x + c1.x, 0.f), fmaxf(x1.y + c1.y, 0.f));
    u.w[3] = pack2(fmaxf(x1.z + c1.z, 0.f), fmaxf(x1.w + c1.w, 0.f));
    return u.v;
}

// ---- prep: blocks [0,512): A' = z_c@W1c + b1 scattered into FRAG-ORDER layout
//            Apf[tile=j>>4][lane][slot] (64 B per lane per tile, coalesced in main);
//            B = z_d@W1d row-major (per-block broadcast read).
//            blocks [512,514): W2 -> MFMA frag layout (hi+lo bf16), zero Srow.
__global__ void prep_kernel(const float* __restrict__ z_c, const float* __restrict__ z_d,
                            const float* __restrict__ W1, const float* __restrict__ b1,
                            const float* __restrict__ W2,
                            float* __restrict__ Apf, float* __restrict__ Bp,
                            uint4* __restrict__ W2hi, uint4* __restrict__ W2lo,
                            float* __restrict__ Srow) {
    if (blockIdx.x < 512) {
        int t = blockIdx.x * 256 + threadIdx.x;
        int sel = t >> 16;            // 0 -> A' (frag-order), 1 -> B (row-major)
        int idx = t & 0xffff;
        int n = idx >> 6, h = idx & 63;
        const float* z = (sel ? z_d : z_c) + n * 64;
        const float* w = W1 + (sel ? 4096 : 0) + h;   // W1 (128,64) row-major
        float a0 = sel ? 0.f : b1[h], a1 = 0.f;
        #pragma unroll
        for (int k = 0; k < 64; k += 2) {
            a0 = fmaf(z[k],     w[k * 64],       a0);
            a1 = fmaf(z[k + 1], w[(k + 1) * 64], a1);
        }
        float val = a0 + a1;
        if (sel) {
            Bp[idx] = val;
        } else {
            // frag-order scatter: tile = n>>4; lane = q*16 + (n&15); slot = s*8 + e
            int s = h >> 5, kk = h & 31, q = kk >> 3, e = kk & 7;
            int lane = q * 16 + (n & 15);
            Apf[(n >> 4) * 1024 + lane * 16 + s * 8 + e] = val;
        }
    } else {
        int tt = (blockIdx.x - 512) * 256 + threadIdx.x;   // 0..511
        Srow[tt] = 0.f; Srow[tt + 512] = 0.f;
        int f = tt >> 6, lane = tt & 63;                   // f = s*4 + t
        int s = f >> 2, t4 = f & 3, q = lane >> 4, l15 = lane & 15;
        int n = t4 * 16 + l15;
        unsigned hi[4], lo[4];
        #pragma unroll
        for (int p = 0; p < 4; ++p) {
            int k = s * 32 + q * 8 + 2 * p;
            float w0 = W2[k * 64 + n], w1 = W2[(k + 1) * 64 + n];
            unsigned h0 = rne_u(w0) >> 16, h1 = rne_u(w1) >> 16;
            hi[p] = h0 | (h1 << 16);
            lo[p] = pair_pack(w0 - bf16_up_bits(h0), w1 - bf16_up_bits(h1));
        }
        W2hi[f * 64 + lane] = make_uint4(hi[0], hi[1], hi[2], hi[3]);
        W2lo[f * 64 + lane] = make_uint4(lo[0], lo[1], lo[2], lo[3]);
    }
}

// ---- main: block = (i, quarter). 4096 blocks x 256 thr; each wave 4 j-tiles of 16.
// Frag-order Apf loads (coalesced, lane-stride 64 B) + 2-deep tile pipeline.
// Operand-swapped MFMA (W2-frag as A, h1-frag as B): acc[t][r] =
// h2pre[j = jb + l15][h = t*16 + q*4 + r], acc initialized to b2.
__global__ void __launch_bounds__(256, 4)
main_kernel(const float* __restrict__ Apf, const float* __restrict__ Bp,
            const uint4* __restrict__ W2hi, const uint4* __restrict__ W2lo,
            const float* __restrict__ b2, const float* __restrict__ Wo,
            float* __restrict__ Srow, float* __restrict__ T0row) {
    const int i       = blockIdx.x >> 2;
    const int quarter = blockIdx.x & 3;
    const int lane = threadIdx.x & 63;
    const int wave = threadIdx.x >> 6;
    const int l15  = lane & 15;
    const int q    = lane >> 4;

    // W2 fragments: 16 coalesced dwordx4 loads (L1/L2-hot, identical per wave)
    bf16x8 whi[2][4], wlo[2][4];
    #pragma unroll
    for (int f = 0; f < 8; ++f) {
        U16 a, b;
        a.u = W2hi[f * 64 + lane];
        b.u = W2lo[f * 64 + lane];
        whi[f >> 2][f & 3] = a.v;
        wlo[f >> 2][f & 3] = b.v;
    }

    // B_i per-lane slice, k = s*32 + q*8 + e (row-major Bp)
    const float* bpr = Bp + i * 64 + q * 8;
    float4 c00 = *(const float4*)(bpr);
    float4 c01 = *(const float4*)(bpr + 4);
    float4 c10 = *(const float4*)(bpr + 32);
    float4 c11 = *(const float4*)(bpr + 36);

    // b2 folded into acc init; Wo per-lane, element (t,r) is h = t*16 + q*4 + r
    f32x4 b2v[4];
    float wov[4][4];
    #pragma unroll
    for (int t = 0; t < 4; ++t) {
        float4 bt = *(const float4*)(b2 + t * 16 + q * 4);
        float4 wt = *(const float4*)(Wo + t * 16 + q * 4);
        b2v[t] = (f32x4){bt.x, bt.y, bt.z, bt.w};
        wov[t][0] = wt.x; wov[t][1] = wt.y; wov[t][2] = wt.z; wov[t][3] = wt.w;
    }

    // frag-order Ap: this wave's 4 tiles start at tile index quarter*16 + wave*4
    const int tbase = quarter * 16 + wave * 4;
    const float* apf = Apf + tbase * 1024 + lane * 16;

    // 2-deep pipeline: X[b] holds one tile's 16 floats (4 x float4, lane-contig 64 B)
    float4 X[2][4];
    #pragma unroll
    for (int p = 0; p < 4; ++p) X[0][p] = ((const float4*)apf)[p];
    #pragma unroll
    for (int p = 0; p < 4; ++p) X[1][p] = ((const float4*)(apf + 1024))[p];

    float sacc = 0.f;

    #pragma unroll
    for (int tile = 0; tile < 4; ++tile) {
        const int b = tile & 1;
        bf16x8 a0 = mk_frag(X[b][0], X[b][1], c00, c01);   // k 0..31
        bf16x8 a1 = mk_frag(X[b][2], X[b][3], c10, c11);   // k 32..63
        if (tile < 2) {                                     // prefetch tile+2
            const float* nx = apf + (tile + 2) * 1024;
            #pragma unroll
            for (int p = 0; p < 4; ++p) X[b][p] = ((const float4*)nx)[p];
        }

        f32x4 acc[4];
        #pragma unroll
        for (int t = 0; t < 4; ++t) acc[t] = b2v[t];   // h2pre + b2 for free
        #pragma unroll
        for (int t = 0; t < 4; ++t) {
            acc[t] = __builtin_amdgcn_mfma_f32_16x16x32_bf16(whi[0][t], a0, acc[t], 0, 0, 0);
            acc[t] = __builtin_amdgcn_mfma_f32_16x16x32_bf16(whi[1][t], a1, acc[t], 0, 0, 0);
            acc[t] = __builtin_amdgcn_mfma_f32_16x16x32_bf16(wlo[0][t], a0, acc[t], 0, 0, 0);
            acc[t] = __builtin_amdgcn_mfma_f32_16x16x32_bf16(wlo[1][t], a1, acc[t], 0, 0, 0);
        }

        // T1[j] = sum_h relu(acc)*Wo: 4 parallel chains + tree, then 2 shfls
        float p0 = 0.f, p1 = 0.f, p2 = 0.f, p3 = 0.f;
        #pragma unroll
        for (int t = 0; t < 4; ++t) {
            p0 = fmaf(fmaxf(acc[t][0], 0.f), wov[t][0], p0);
            p1 = fmaf(fmaxf(acc[t][1], 0.f), wov[t][1], p1);
            p2 = fmaf(fmaxf(acc[t][2], 0.f), wov[t][2], p2);
            p3 = fmaf(fmaxf(acc[t][3], 0.f), wov[t][3], p3);
        }
        float psum = (p0 + p1) + (p2 + p3);
        psum += __shfl_xor(psum, 16);
        psum += __shfl_xor(psum, 32);   // T1[j], replicated over the 4 q-groups

        const int j = (tbase + tile) * 16 + l15;
        if (j == i && q == 0) T0row[i] = psum;   // diagonal: exactly one writer
        sacc += __expf(psum);
    }

    // reduce over l15 only (q-groups are exact replicas -> exact sum, no 4x factor)
    sacc += __shfl_xor(sacc, 1);
    sacc += __shfl_xor(sacc, 2);
    sacc += __shfl_xor(sacc, 4);
    sacc += __shfl_xor(sacc, 8);
    if (lane == 0) atomicAdd(&Srow[i], sacc);   // 16 adds per i, 1024 addresses
}

// ---- combine+finish: 1 block x 1024 thr. bound = mean(T0) - (mean(log Srow) - ln N)
__global__ void __launch_bounds__(1024)
combine_finish(const float* __restrict__ Srow, const float* __restrict__ T0row,
               float* __restrict__ out) {
    int i = threadIdx.x;
    float l  = logf(Srow[i]);
    float t0 = T0row[i];
    #pragma unroll
    for (int off = 1; off < 64; off <<= 1) {
        l  += __shfl_xor(l, off);
        t0 += __shfl_xor(t0, off);
    }
    __shared__ float sl[16], st[16];
    int w = threadIdx.x >> 6;
    if ((threadIdx.x & 63) == 0) { sl[w] = l; st[w] = t0; }
    __syncthreads();
    if (threadIdx.x == 0) {
        float L = 0.f, T = 0.f;
        #pragma unroll
        for (int k = 0; k < 16; ++k) { L += sl[k]; T += st[k]; }
        out[0] = (T - L) * (1.0f / 1024.0f) + 6.9314718055994531f;
    }
}

extern "C" void kernel_launch(void* const* d_in, const int* in_sizes, int n_in,
                              void* d_out, int out_size, void* d_ws, size_t ws_size,
                              hipStream_t stream) {
    const float* z_c = (const float*)d_in[0];
    const float* z_d = (const float*)d_in[1];
    const float* W1  = (const float*)d_in[2];
    const float* b1  = (const float*)d_in[3];
    const float* W2  = (const float*)d_in[4];
    const float* b2  = (const float*)d_in[5];
    const float* Wo  = (const float*)d_in[6];
    // d_in[7] = bo: shifts T0.mean and every LSE equally -> cancels; omitted.
    float* out   = (float*)d_out;

    float* Apf   = (float*)d_ws;                 // 65536 fp32, frag-order
    float* Bp    = Apf + NN * 64;                // 65536 fp32, row-major
    uint4* W2hi  = (uint4*)(Bp + NN * 64);       // 512 uint4 (8 KB)
    uint4* W2lo  = W2hi + 512;                   // 512 uint4 (8 KB)
    float* Srow  = (float*)(W2lo + 512);         // 1024 fp32
    float* T0row = Srow + NN;                    // 1024 fp32

    prep_kernel<<<514, 256, 0, stream>>>(z_c, z_d, W1, b1, W2, Apf, Bp, W2hi, W2lo, Srow);
    main_kernel<<<4096, 256, 0, stream>>>(Apf, Bp, W2hi, W2lo, b2, Wo, Srow, T0row);
    combine_finish<<<1, 1024, 0, stream>>>(Srow, T0row, out);
}

// Round 7
// 113.426 us; speedup vs baseline: 1.7998x; 1.7998x over previous
//
#include <hip/hip_runtime.h>
#include <hip/hip_bf16.h>
#include <math.h>

#define NN 1024

typedef short bf16x8 __attribute__((ext_vector_type(8)));
typedef float f32x4 __attribute__((ext_vector_type(4)));

__device__ __forceinline__ unsigned rne_u(float x) {
    unsigned u = __float_as_uint(x);
    return u + 0x7fffu + ((u >> 16) & 1u);
}
__device__ __forceinline__ float bf16_up_bits(unsigned hi16) {
    return __uint_as_float(hi16 << 16);
}
__device__ __forceinline__ unsigned pair_pack(float a, float b) {   // a->low, b->high, RNE
    return (rne_u(a) >> 16) | (rne_u(b) & 0xffff0000u);
}
// packed fp32x2 -> bf16x2 (v_cvt_pk_bf16_f32 on gfx950)
__device__ __forceinline__ unsigned pack2(float a, float b) {
    __hip_bfloat162 h = __float22bfloat162_rn(make_float2(a, b));
    unsigned u;
    __builtin_memcpy(&u, &h, 4);
    return u;
}

union U16 { uint4 u; bf16x8 v; };
union P4 { unsigned w[4]; bf16x8 v; };

// h1 fragment: relu(x + c) -> bf16 RNE, element e at k = q*8+e
__device__ __forceinline__ bf16x8 mk_frag(float4 x0, float4 x1, float4 c0, float4 c1) {
    P4 u;
    u.w[0] = pack2(fmaxf(x0.x + c0.x, 0.f), fmaxf(x0.y + c0.y, 0.f));
    u.w[1] = pack2(fmaxf(x0.z + c0.z, 0.f), fmaxf(x0.w + c0.w, 0.f));
    u.w[2] = pack2(fmaxf(x1.x + c1.x, 0.f), fmaxf(x1.y + c1.y, 0.f));
    u.w[3] = pack2(fmaxf(x1.z + c1.z, 0.f), fmaxf(x1.w + c1.w, 0.f));
    return u.v;
}

// ---- prep: blocks [0,512): A' = z_c@W1c + b1 scattered into FRAG-ORDER layout
//            Apf[tile=j>>4][lane][slot]; B = z_d@W1d row-major.
//            blocks [512,514): W2 -> MFMA frag layout (hi+lo bf16), zero Srow.
__global__ void prep_kernel(const float* __restrict__ z_c, const float* __restrict__ z_d,
                            const float* __restrict__ W1, const float* __restrict__ b1,
                            const float* __restrict__ W2,
                            float* __restrict__ Apf, float* __restrict__ Bp,
                            uint4* __restrict__ W2hi, uint4* __restrict__ W2lo,
                            float* __restrict__ Srow) {
    if (blockIdx.x < 512) {
        int t = blockIdx.x * 256 + threadIdx.x;
        int sel = t >> 16;            // 0 -> A' (frag-order), 1 -> B (row-major)
        int idx = t & 0xffff;
        int n = idx >> 6, h = idx & 63;
        const float* z = (sel ? z_d : z_c) + n * 64;
        const float* w = W1 + (sel ? 4096 : 0) + h;   // W1 (128,64) row-major
        float a0 = sel ? 0.f : b1[h], a1 = 0.f;
        #pragma unroll
        for (int k = 0; k < 64; k += 2) {
            a0 = fmaf(z[k],     w[k * 64],       a0);
            a1 = fmaf(z[k + 1], w[(k + 1) * 64], a1);
        }
        float val = a0 + a1;
        if (sel) {
            Bp[idx] = val;
        } else {
            // frag-order scatter: tile = n>>4; lane = q*16 + (n&15); slot = s*8 + e
            int s = h >> 5, kk = h & 31, q = kk >> 3, e = kk & 7;
            int lane = q * 16 + (n & 15);
            Apf[(n >> 4) * 1024 + lane * 16 + s * 8 + e] = val;
        }
    } else {
        int tt = (blockIdx.x - 512) * 256 + threadIdx.x;   // 0..511
        Srow[tt] = 0.f; Srow[tt + 512] = 0.f;
        int f = tt >> 6, lane = tt & 63;                   // f = s*4 + t
        int s = f >> 2, t4 = f & 3, q = lane >> 4, l15 = lane & 15;
        int n = t4 * 16 + l15;
        unsigned hi[4], lo[4];
        #pragma unroll
        for (int p = 0; p < 4; ++p) {
            int k = s * 32 + q * 8 + 2 * p;
            float w0 = W2[k * 64 + n], w1 = W2[(k + 1) * 64 + n];
            unsigned h0 = rne_u(w0) >> 16, h1 = rne_u(w1) >> 16;
            hi[p] = h0 | (h1 << 16);
            lo[p] = pair_pack(w0 - bf16_up_bits(h0), w1 - bf16_up_bits(h1));
        }
        W2hi[f * 64 + lane] = make_uint4(hi[0], hi[1], hi[2], hi[3]);
        W2lo[f * 64 + lane] = make_uint4(lo[0], lo[1], lo[2], lo[3]);
    }
}

// ---- main: block = (i, quarter). 4096 blocks x 256 thr; each wave 4 j-tiles of 16.
// REGISTER-DIET version: two h-half passes so only half the W2 fragments (32 regs)
// are live at once; A-frags for all 4 tiles built upfront (32 regs). Target: total
// unified VGPR+AGPR <= 128 -> 4 waves/SIMD residency (fixes the 20%-occupancy wall).
// psum is additive over h (relu/Wo are per-h), so the h-split is numerically exact.
__global__ void __launch_bounds__(256, 4)
main_kernel(const float* __restrict__ Apf, const float* __restrict__ Bp,
            const uint4* __restrict__ W2hi, const uint4* __restrict__ W2lo,
            const float* __restrict__ b2, const float* __restrict__ Wo,
            float* __restrict__ Srow, float* __restrict__ T0row) {
    const int i       = blockIdx.x >> 2;
    const int quarter = blockIdx.x & 3;
    const int lane = threadIdx.x & 63;
    const int wave = threadIdx.x >> 6;
    const int l15  = lane & 15;
    const int q    = lane >> 4;

    const int tbase = quarter * 16 + wave * 4;
    const float* apf = Apf + tbase * 1024 + lane * 16;

    // B_i per-lane slice, k = s*32 + q*8 + e  (dead after frag build)
    const float* bpr = Bp + i * 64 + q * 8;
    float4 c00 = *(const float4*)(bpr);
    float4 c01 = *(const float4*)(bpr + 4);
    float4 c10 = *(const float4*)(bpr + 32);
    float4 c11 = *(const float4*)(bpr + 36);

    // Build A-frags for all 4 tiles upfront (frag-order loads: lane-contig 64 B)
    bf16x8 A0[4], A1[4];
    #pragma unroll
    for (int tile = 0; tile < 4; ++tile) {
        const float4* p = (const float4*)(apf + tile * 1024);
        float4 x0 = p[0], x1 = p[1], x2 = p[2], x3 = p[3];
        A0[tile] = mk_frag(x0, x1, c00, c01);   // k 0..31
        A1[tile] = mk_frag(x2, x3, c10, c11);   // k 32..63
    }

    float psum[4] = {0.f, 0.f, 0.f, 0.f};

    // Two passes over h-halves; W2 frags for one half only (32 regs) live at a time.
    for (int th = 0; th < 2; ++th) {
        bf16x8 whi[2][2], wlo[2][2];   // [s][t-within-half]
        #pragma unroll
        for (int s = 0; s < 2; ++s)
            #pragma unroll
            for (int t = 0; t < 2; ++t) {
                int f = s * 4 + th * 2 + t;
                U16 a, b;
                a.u = W2hi[f * 64 + lane];
                b.u = W2lo[f * 64 + lane];
                whi[s][t] = a.v; wlo[s][t] = b.v;
            }
        f32x4 b2v[2];
        float wov[2][4];
        #pragma unroll
        for (int t = 0; t < 2; ++t) {
            float4 bt = *(const float4*)(b2 + th * 32 + t * 16 + q * 4);
            float4 wt = *(const float4*)(Wo + th * 32 + t * 16 + q * 4);
            b2v[t] = (f32x4){bt.x, bt.y, bt.z, bt.w};
            wov[t][0] = wt.x; wov[t][1] = wt.y; wov[t][2] = wt.z; wov[t][3] = wt.w;
        }

        #pragma unroll
        for (int tile = 0; tile < 4; ++tile) {
            f32x4 acc0 = b2v[0], acc1 = b2v[1];   // b2 folded into init
            acc0 = __builtin_amdgcn_mfma_f32_16x16x32_bf16(whi[0][0], A0[tile], acc0, 0, 0, 0);
            acc1 = __builtin_amdgcn_mfma_f32_16x16x32_bf16(whi[0][1], A0[tile], acc1, 0, 0, 0);
            acc0 = __builtin_amdgcn_mfma_f32_16x16x32_bf16(whi[1][0], A1[tile], acc0, 0, 0, 0);
            acc1 = __builtin_amdgcn_mfma_f32_16x16x32_bf16(whi[1][1], A1[tile], acc1, 0, 0, 0);
            acc0 = __builtin_amdgcn_mfma_f32_16x16x32_bf16(wlo[0][0], A0[tile], acc0, 0, 0, 0);
            acc1 = __builtin_amdgcn_mfma_f32_16x16x32_bf16(wlo[0][1], A0[tile], acc1, 0, 0, 0);
            acc0 = __builtin_amdgcn_mfma_f32_16x16x32_bf16(wlo[1][0], A1[tile], acc0, 0, 0, 0);
            acc1 = __builtin_amdgcn_mfma_f32_16x16x32_bf16(wlo[1][1], A1[tile], acc1, 0, 0, 0);

            // partial T1 over this h-half: per lane h = (th*2 + t)*16 + q*4 + r
            float p0 = 0.f, p1 = 0.f, p2 = 0.f, p3 = 0.f;
            p0 = fmaf(fmaxf(acc0[0], 0.f), wov[0][0], p0);
            p1 = fmaf(fmaxf(acc0[1], 0.f), wov[0][1], p1);
            p2 = fmaf(fmaxf(acc0[2], 0.f), wov[0][2], p2);
            p3 = fmaf(fmaxf(acc0[3], 0.f), wov[0][3], p3);
            p0 = fmaf(fmaxf(acc1[0], 0.f), wov[1][0], p0);
            p1 = fmaf(fmaxf(acc1[1], 0.f), wov[1][1], p1);
            p2 = fmaf(fmaxf(acc1[2], 0.f), wov[1][2], p2);
            p3 = fmaf(fmaxf(acc1[3], 0.f), wov[1][3], p3);
            psum[tile] += (p0 + p1) + (p2 + p3);
        }
    }

    // Epilogue: 4 independent reduce/exp chains
    float sacc = 0.f;
    #pragma unroll
    for (int tile = 0; tile < 4; ++tile) {
        float ps = psum[tile];
        ps += __shfl_xor(ps, 16);
        ps += __shfl_xor(ps, 32);   // T1[j], replicated over the 4 q-groups
        const int j = (tbase + tile) * 16 + l15;
        if (j == i && q == 0) T0row[i] = ps;   // diagonal: exactly one writer
        sacc += __expf(ps);
    }
    // reduce over l15 only (q-groups are exact replicas -> exact sum)
    sacc += __shfl_xor(sacc, 1);
    sacc += __shfl_xor(sacc, 2);
    sacc += __shfl_xor(sacc, 4);
    sacc += __shfl_xor(sacc, 8);
    if (lane == 0) atomicAdd(&Srow[i], sacc);   // 16 adds per i, 1024 addresses
}

// ---- combine+finish: 1 block x 1024 thr. bound = mean(T0) - (mean(log Srow) - ln N)
__global__ void __launch_bounds__(1024)
combine_finish(const float* __restrict__ Srow, const float* __restrict__ T0row,
               float* __restrict__ out) {
    int i = threadIdx.x;
    float l  = logf(Srow[i]);
    float t0 = T0row[i];
    #pragma unroll
    for (int off = 1; off < 64; off <<= 1) {
        l  += __shfl_xor(l, off);
        t0 += __shfl_xor(t0, off);
    }
    __shared__ float sl[16], st[16];
    int w = threadIdx.x >> 6;
    if ((threadIdx.x & 63) == 0) { sl[w] = l; st[w] = t0; }
    __syncthreads();
    if (threadIdx.x == 0) {
        float L = 0.f, T = 0.f;
        #pragma unroll
        for (int k = 0; k < 16; ++k) { L += sl[k]; T += st[k]; }
        out[0] = (T - L) * (1.0f / 1024.0f) + 6.9314718055994531f;
    }
}

extern "C" void kernel_launch(void* const* d_in, const int* in_sizes, int n_in,
                              void* d_out, int out_size, void* d_ws, size_t ws_size,
                              hipStream_t stream) {
    const float* z_c = (const float*)d_in[0];
    const float* z_d = (const float*)d_in[1];
    const float* W1  = (const float*)d_in[2];
    const float* b1  = (const float*)d_in[3];
    const float* W2  = (const float*)d_in[4];
    const float* b2  = (const float*)d_in[5];
    const float* Wo  = (const float*)d_in[6];
    // d_in[7] = bo: shifts T0.mean and every LSE equally -> cancels; omitted.
    float* out   = (float*)d_out;

    float* Apf   = (float*)d_ws;                 // 65536 fp32, frag-order
    float* Bp    = Apf + NN * 64;                // 65536 fp32, row-major
    uint4* W2hi  = (uint4*)(Bp + NN * 64);       // 512 uint4 (8 KB)
    uint4* W2lo  = W2hi + 512;                   // 512 uint4 (8 KB)
    float* Srow  = (float*)(W2lo + 512);         // 1024 fp32
    float* T0row = Srow + NN;                    // 1024 fp32

    prep_kernel<<<514, 256, 0, stream>>>(z_c, z_d, W1, b1, W2, Apf, Bp, W2hi, W2lo, Srow);
    main_kernel<<<4096, 256, 0, stream>>>(Apf, Bp, W2hi, W2lo, b2, Wo, Srow, T0row);
    combine_finish<<<1, 1024, 0, stream>>>(Srow, T0row, out);
}